// Round 2
// baseline (232.754 us; speedup 1.0000x reference)
//
#include <hip/hip_runtime.h>

// Pre-emphasis IIR: out[t] = y[t] + 0.85*out[t-1], shift by SKIP=91,
// scale 32768, clip [-32768,32767], astype(int16) (trunc toward zero).
// Harness reads d_out as int32 -> we store the int16 values as int32.
//
// Approximation: 0.85^67 ~ 1.9e-5, so a 67-sample warm-up reproduces the
// exact scan to ~2 units on the 32768 scale (threshold is 655).

#define BLOCK   256
#define CH      32                  // outputs per thread
#define TILE    (BLOCK * CH)        // 8192 outputs per block
#define SKIP    91
#define WARM    67                  // SKIP-WARM = 24 -> 16B-aligned tile start
#define COEF    0.85f
#define LOADN   (TILE + WARM + 1)   // 8260, multiple of 4
#define PAD(p)  ((p) + ((p) >> 5))  // stride-32 -> 33: 2-way bank alias (free)
#define LDS_SZ  8520                // > PAD(LOADN-1) = 8517

__global__ __launch_bounds__(BLOCK) void preemph_kernel(
        const float* __restrict__ sig, int* __restrict__ out, int n) {
    __shared__ float lds[LDS_SZ];
    const int  tid      = threadIdx.x;
    const long tileBase = (long)blockIdx.x * TILE;
    const long tStart   = tileBase + (SKIP - WARM);   // tileBase + 24, 16B aligned

    // Phase 1: coalesced float4 global -> LDS (padded), zero past end-of-signal.
    for (int base = 0; base < LOADN; base += BLOCK * 4) {
        int off = base + tid * 4;
        if (off < LOADN) {
            long t = tStart + off;
            float4 v;
            if (t + 3 < (long)n) {
                v = *reinterpret_cast<const float4*>(sig + t);
            } else {
                v.x = (t + 0 < (long)n) ? sig[t + 0] : 0.f;
                v.y = (t + 1 < (long)n) ? sig[t + 1] : 0.f;
                v.z = (t + 2 < (long)n) ? sig[t + 2] : 0.f;
                v.w = (t + 3 < (long)n) ? sig[t + 3] : 0.f;
            }
            lds[PAD(off + 0)] = v.x;
            lds[PAD(off + 1)] = v.y;
            lds[PAD(off + 2)] = v.z;
            lds[PAD(off + 3)] = v.w;
        }
    }
    __syncthreads();

    // Phase 2: per-thread truncated scan (67 warm-up + 32 outputs) from LDS.
    float acc = 0.f;
    const int b0 = tid * CH;
#pragma unroll
    for (int j = 0; j < WARM; ++j) {
        int p = b0 + j;
        acc = fmaf(acc, COEF, lds[PAD(p)]);
    }
    int res[CH];
    const long oBase = tileBase + b0;
    const long oLim  = (long)n - SKIP;   // outputs >= n-SKIP are zero-padded
#pragma unroll
    for (int j = 0; j < CH; ++j) {
        int p = b0 + WARM + j;
        acc = fmaf(acc, COEF, lds[PAD(p)]);
        float v = acc * 32768.f;
        v = fminf(fmaxf(v, -32768.f), 32767.f);
        int iv = (int)v;                  // v_cvt_i32_f32: trunc toward zero
        long o = oBase + j;
        res[j] = (o < oLim) ? iv : 0;
    }
    __syncthreads();

    // Phase 3: int results -> LDS (bit-cast) so the global store coalesces.
#pragma unroll
    for (int j = 0; j < CH; ++j) {
        int p = b0 + j;
        lds[PAD(p)] = __int_as_float(res[j]);
    }
    __syncthreads();

    // Phase 4: coalesced 16B store of raw int32 bits.
    for (int base = 0; base < TILE; base += BLOCK * 4) {
        int off = base + tid * 4;
        long o  = tileBase + off;
        if (o < (long)n) {
            int4 v;
            v.x = __float_as_int(lds[PAD(off + 0)]);
            v.y = __float_as_int(lds[PAD(off + 1)]);
            v.z = __float_as_int(lds[PAD(off + 2)]);
            v.w = __float_as_int(lds[PAD(off + 3)]);
            if (o + 3 < (long)n) {
                *reinterpret_cast<int4*>(out + o) = v;
            } else {
                if (o + 0 < (long)n) out[o + 0] = v.x;
                if (o + 1 < (long)n) out[o + 1] = v.y;
                if (o + 2 < (long)n) out[o + 2] = v.z;
            }
        }
    }
}

extern "C" void kernel_launch(void* const* d_in, const int* in_sizes, int n_in,
                              void* d_out, int out_size, void* d_ws, size_t ws_size,
                              hipStream_t stream) {
    const float* sig = (const float*)d_in[0];
    int* out = (int*)d_out;
    int n = in_sizes[0];
    int grid = (int)(((long)n + TILE - 1) / TILE);
    preemph_kernel<<<grid, BLOCK, 0, stream>>>(sig, out, n);
}

// Round 3
// 232.696 us; speedup vs baseline: 1.0002x; 1.0002x over previous
//
#include <hip/hip_runtime.h>

// Pre-emphasis IIR: out[t] = y[t] + 0.85*out[t-1], shift by SKIP=91,
// scale 32768, clip [-32768,32767], astype(int16) (trunc toward zero).
// Harness reads d_out as int32 -> store int16 values as int32.
//
// Approximation: 0.85^67 ~ 1.9e-5 -> 67-sample warm-up reproduces the exact
// scan to ~2 units on the 32768 scale (threshold 655; measured absmax 128
// comes from trunc-boundary flips, well within threshold).
//
// R2 -> R3: CH 32->16 (TILE 8192->4096, LDS 33.5->17.2 KB) to lift the
// occupancy cap from 16 to 32 waves/CU (R2: Occupancy 37%, hbm 30%, VALU 21%
// -> latency-bound on resident-block count).

#define BLOCK   256
#define CH      16                  // outputs per thread
#define TILE    (BLOCK * CH)        // 4096 outputs per block
#define SKIP    91
#define WARM    67                  // SKIP-WARM = 24 -> 16B-aligned tile start
#define COEF    0.85f
#define LOADN   (TILE + WARM + 1)   // 4164, multiple of 4
#define PAD(p)  ((p) + ((p) >> 5))  // stride 32->33: 2-way bank alias (free)
#define LDS_SZ  4300                // > PAD(LOADN-1) = 4293

__global__ __launch_bounds__(BLOCK) void preemph_kernel(
        const float* __restrict__ sig, int* __restrict__ out, int n) {
    __shared__ float lds[LDS_SZ];
    const int  tid      = threadIdx.x;
    const long tileBase = (long)blockIdx.x * TILE;
    const long tStart   = tileBase + (SKIP - WARM);   // tileBase + 24, 16B aligned

    // Phase 1: coalesced float4 global -> LDS (padded), zero past end-of-signal.
    for (int base = 0; base < LOADN; base += BLOCK * 4) {
        int off = base + tid * 4;
        if (off < LOADN) {
            long t = tStart + off;
            float4 v;
            if (t + 3 < (long)n) {
                v = *reinterpret_cast<const float4*>(sig + t);
            } else {
                v.x = (t + 0 < (long)n) ? sig[t + 0] : 0.f;
                v.y = (t + 1 < (long)n) ? sig[t + 1] : 0.f;
                v.z = (t + 2 < (long)n) ? sig[t + 2] : 0.f;
                v.w = (t + 3 < (long)n) ? sig[t + 3] : 0.f;
            }
            lds[PAD(off + 0)] = v.x;
            lds[PAD(off + 1)] = v.y;
            lds[PAD(off + 2)] = v.z;
            lds[PAD(off + 3)] = v.w;
        }
    }
    __syncthreads();

    // Phase 2: per-thread truncated scan (67 warm-up + 16 outputs) from LDS.
    float acc = 0.f;
    const int b0 = tid * CH;
#pragma unroll
    for (int j = 0; j < WARM; ++j) {
        int p = b0 + j;
        acc = fmaf(acc, COEF, lds[PAD(p)]);
    }
    int res[CH];
    const long oBase = tileBase + b0;
    const long oLim  = (long)n - SKIP;   // outputs >= n-SKIP are zero-padded
#pragma unroll
    for (int j = 0; j < CH; ++j) {
        int p = b0 + WARM + j;
        acc = fmaf(acc, COEF, lds[PAD(p)]);
        float v = acc * 32768.f;
        v = fminf(fmaxf(v, -32768.f), 32767.f);
        int iv = (int)v;                  // v_cvt_i32_f32: trunc toward zero
        long o = oBase + j;
        res[j] = (o < oLim) ? iv : 0;
    }
    __syncthreads();

    // Phase 3: int results -> LDS (bit-cast) so the global store coalesces.
#pragma unroll
    for (int j = 0; j < CH; ++j) {
        int p = b0 + j;
        lds[PAD(p)] = __int_as_float(res[j]);
    }
    __syncthreads();

    // Phase 4: coalesced 16B store of raw int32 bits.
    for (int base = 0; base < TILE; base += BLOCK * 4) {
        int off = base + tid * 4;
        long o  = tileBase + off;
        if (o < (long)n) {
            int4 v;
            v.x = __float_as_int(lds[PAD(off + 0)]);
            v.y = __float_as_int(lds[PAD(off + 1)]);
            v.z = __float_as_int(lds[PAD(off + 2)]);
            v.w = __float_as_int(lds[PAD(off + 3)]);
            if (o + 3 < (long)n) {
                *reinterpret_cast<int4*>(out + o) = v;
            } else {
                if (o + 0 < (long)n) out[o + 0] = v.x;
                if (o + 1 < (long)n) out[o + 1] = v.y;
                if (o + 2 < (long)n) out[o + 2] = v.z;
            }
        }
    }
}

extern "C" void kernel_launch(void* const* d_in, const int* in_sizes, int n_in,
                              void* d_out, int out_size, void* d_ws, size_t ws_size,
                              hipStream_t stream) {
    const float* sig = (const float*)d_in[0];
    int* out = (int*)d_out;
    int n = in_sizes[0];
    int grid = (int)(((long)n + TILE - 1) / TILE);
    preemph_kernel<<<grid, BLOCK, 0, stream>>>(sig, out, n);
}